// Round 8
// baseline (254.744 us; speedup 1.0000x reference)
//
#include <hip/hip_runtime.h>
#include <hip/hip_bf16.h>

#define H 32
#define HKV 8
#define DD 128
#define SMAX 1024
#define QBLK 32            // q rows per wave (per head)
#define KVBLK 64
#define NQB (SMAX / QBLK)  // 32
#define QSCALE 0.12751770f // (1/sqrt(128)) * log2(e) — exp2-domain softmax

typedef __attribute__((ext_vector_type(8))) short bf16x8;
typedef __attribute__((ext_vector_type(4))) float f32x4;
typedef __attribute__((ext_vector_type(2))) unsigned int u32x2;

// HW packed f32->bf16 (RNE), 2 values per instruction. dst = {lo:a, hi:b}.
__device__ inline unsigned cvt_pk_bf16(float a, float b) {
  unsigned r;
  asm("v_cvt_pk_bf16_f32 %0, %1, %2" : "=v"(r) : "v"(a), "v"(b));
  return r;
}

// 16B-granular XOR swizzle (bits 4..6 only): preserves 16B alignment so all
// fragment reads are single ds_read_b128. Over 16 consecutive rows the key
// takes 8 values; a wave's 64 b128 lanes tile all 32 banks exactly (floor).
__device__ inline int swz16(int x) { return ((x ^ (x >> 3)) & 7) << 4; }

__global__ __launch_bounds__(256) void fa_kernel(
    const float* __restrict__ q, const float* __restrict__ k,
    const float* __restrict__ v, const int* __restrict__ cu,
    float* __restrict__ out, int inner_n) {
  const int bx = blockIdx.x;
  const int inner = bx % inner_n;
  const int qb = NQB - 1 - (bx / inner_n);  // big q-blocks dispatch first
  const int b = inner / HKV;
  const int kvh = inner % HKV;

  const int seq_start = cu[b];
  const int seq_len = cu[b + 1] - seq_start;
  if (qb * QBLK >= seq_len) return;

  const int tid = threadIdx.x;
  const int lane = tid & 63;
  const int w = tid >> 6;
  const int lg = lane >> 4;
  const int lr = lane & 15;
  const int h = kvh * (H / HKV) + w;  // wave w owns head kvh*4+w

  __shared__ __align__(16) char kbuf[2][KVBLK * DD * 2];    // [64 kv][128 d]
  __shared__ __align__(16) char vbuf[2][DD * KVBLK * 2];    // [128 d][64 kv] V^T
  __shared__ __align__(16) char pbuf[4][QBLK * KVBLK * 2];  // per-wave [32 q][64 kv]

  const float* kbase = k + (size_t)seq_start * (HKV * DD) + kvh * DD;
  const float* vbase = v + (size_t)seq_start * (HKV * DD) + kvh * DD;

  float4 reg[8];  // ONE shared staging block (K-phase, then V-phase)

#define LOAD_T(BASE, T)                                                   \
  do {                                                                    \
    int rbase_ = (T)*KVBLK;                                               \
    _Pragma("unroll") for (int i = 0; i < 8; ++i) {                       \
      int f4_ = i * 256 + tid;                                            \
      int row_ = f4_ >> 5;                                                \
      int c4_ = f4_ & 31;                                                 \
      size_t off_ =                                                       \
          (size_t)min(rbase_ + row_, seq_len - 1) * (HKV * DD) + c4_ * 4; \
      reg[i] = *(const float4*)((BASE) + off_);                           \
    }                                                                     \
  } while (0)

#define STORE_K(BI)                                                       \
  do {                                                                    \
    char* kb_ = kbuf[BI];                                                 \
    _Pragma("unroll") for (int i = 0; i < 8; ++i) {                       \
      int f4_ = i * 256 + tid;                                            \
      int row_ = f4_ >> 5;                                                \
      int c4_ = f4_ & 31;                                                 \
      u32x2 u_;                                                           \
      u_[0] = cvt_pk_bf16(reg[i].x, reg[i].y);                            \
      u_[1] = cvt_pk_bf16(reg[i].z, reg[i].w);                            \
      *(u32x2*)(kb_ + row_ * 256 + ((c4_ * 8) ^ swz16(row_))) = u_;       \
    }                                                                     \
  } while (0)

#define STORE_V(BI)                                                       \
  do {                                                                    \
    char* vb_ = vbuf[BI];                                                 \
    _Pragma("unroll") for (int i = 0; i < 8; ++i) {                       \
      int f4_ = i * 256 + tid;                                            \
      int row_ = f4_ >> 5;                                                \
      int c4_ = f4_ & 31;                                                 \
      unsigned ab_ = cvt_pk_bf16(reg[i].x, reg[i].y);                     \
      unsigned cd_ = cvt_pk_bf16(reg[i].z, reg[i].w);                     \
      int d0_ = 4 * c4_;                                                  \
      *(unsigned short*)(vb_ + (d0_ + 0) * 128 + ((row_ * 2) ^ swz16(d0_ + 0))) = (unsigned short)ab_;         \
      *(unsigned short*)(vb_ + (d0_ + 1) * 128 + ((row_ * 2) ^ swz16(d0_ + 1))) = (unsigned short)(ab_ >> 16); \
      *(unsigned short*)(vb_ + (d0_ + 2) * 128 + ((row_ * 2) ^ swz16(d0_ + 2))) = (unsigned short)cd_;         \
      *(unsigned short*)(vb_ + (d0_ + 3) * 128 + ((row_ * 2) ^ swz16(d0_ + 3))) = (unsigned short)(cd_ >> 16); \
    }                                                                     \
  } while (0)

  // ---- prologue: K(0) loads in flight while Q fragments load ----
  LOAD_T(kbase, 0);

  bf16x8 qf[2][4];  // Q * (scale*log2e); row=lr, k = 8*lg + 32*ks + [0..7]
#pragma unroll
  for (int m = 0; m < 2; ++m) {
    int q_pos = qb * QBLK + m * 16 + lr;
    int q_tok = seq_start + min(q_pos, seq_len - 1);
    const float* qp = q + (size_t)q_tok * (H * DD) + h * DD;
#pragma unroll
    for (int ks = 0; ks < 4; ++ks) {
      int d0 = 8 * lg + 32 * ks;
      float4 x = *(const float4*)(qp + d0);
      float4 y = *(const float4*)(qp + d0 + 4);
      u32x2 lo, hi;
      lo[0] = cvt_pk_bf16(x.x * QSCALE, x.y * QSCALE);
      lo[1] = cvt_pk_bf16(x.z * QSCALE, x.w * QSCALE);
      hi[0] = cvt_pk_bf16(y.x * QSCALE, y.y * QSCALE);
      hi[1] = cvt_pk_bf16(y.z * QSCALE, y.w * QSCALE);
      union { u32x2 u[2]; bf16x8 v; } cvt;
      cvt.u[0] = lo; cvt.u[1] = hi;
      qf[m][ks] = cvt.v;
    }
  }

  f32x4 o[2][8];
#pragma unroll
  for (int m = 0; m < 2; ++m)
#pragma unroll
    for (int i = 0; i < 8; ++i) o[m][i] = (f32x4){0.f, 0.f, 0.f, 0.f};
  float m_run[2], l_run[2];  // per-lane stats for q-row = m*16 + lr (S^T layout)
#pragma unroll
  for (int m = 0; m < 2; ++m) { m_run[m] = -1e30f; l_run[m] = 0.f; }

  char* pw = pbuf[w];
  const int qmax = qb * QBLK + QBLK - 1;
  const int tmax = qmax >> 6;
  const int pkey[2] = {swz16(lr), swz16(16 + lr)};

  STORE_K(0);
  LOAD_T(vbase, 0);
  STORE_V(0);
  __syncthreads();

  for (int t = 0; t <= tmax; ++t) {
    const int cur = t & 1;
    const int nxt = cur ^ 1;
    const char* kb_ = kbuf[cur];
    const char* vb_ = vbuf[cur];

    if (t < tmax) LOAD_T(kbase, t + 1);  // latency hides under QK^T
    __builtin_amdgcn_sched_barrier(0);

    // ---- QK^T (SWAPPED: mfma(K, Q) -> S^T). Lane holds S[kv=16n+4lg+r][q=m16+lr].
    f32x4 s[2][4];
    __builtin_amdgcn_s_setprio(1);
#pragma unroll
    for (int n = 0; n < 4; ++n) {
      if (t * 64 + n * 16 <= qmax) {
        int krow = n * 16 + lr;
        int key = swz16(krow);
        bf16x8 kb4[4];
#pragma unroll
        for (int ks = 0; ks < 4; ++ks)
          kb4[ks] = *(const bf16x8*)(kb_ + krow * 256 + ((16 * lg + 64 * ks) ^ key));
#pragma unroll
        for (int m = 0; m < 2; ++m) {
          f32x4 acc = {0.f, 0.f, 0.f, 0.f};
#pragma unroll
          for (int ks = 0; ks < 4; ++ks)
            acc = __builtin_amdgcn_mfma_f32_16x16x32_bf16(kb4[ks], qf[m][ks], acc, 0, 0, 0);
          s[m][n] = acc;
        }
      } else {
        s[0][n] = (f32x4){-2e30f, -2e30f, -2e30f, -2e30f};
        s[1][n] = s[0][n];
      }
    }
    __builtin_amdgcn_s_setprio(0);

    if (t < tmax) {
      STORE_K(nxt);
      LOAD_T(vbase, t + 1);
    }
    __builtin_amdgcn_sched_barrier(0);

    // ---- causal mask on diagonal tile: kv = t*64+16n+4lg+r, q = qb*32+m16+lr ----
    if (t == tmax) {
#pragma unroll
      for (int n = 0; n < 4; ++n) {
        int kv_pos = t * 64 + n * 16 + 4 * lg;
#pragma unroll
        for (int m = 0; m < 2; ++m) {
          int qrow = qb * QBLK + m * 16 + lr;
#pragma unroll
          for (int r = 0; r < 4; ++r)
            if (kv_pos + r > qrow) s[m][n][r] = -2e30f;
        }
      }
    }

    // ---- online softmax in S^T: per-lane row reduce + 2 shfls ----
#pragma unroll
    for (int m = 0; m < 2; ++m) {
      float mx = fmaxf(
          fmaxf(fmaxf(fmaxf(s[m][0][0], s[m][0][1]), fmaxf(s[m][0][2], s[m][0][3])),
                fmaxf(fmaxf(s[m][1][0], s[m][1][1]), fmaxf(s[m][1][2], s[m][1][3]))),
          fmaxf(fmaxf(fmaxf(s[m][2][0], s[m][2][1]), fmaxf(s[m][2][2], s[m][2][3])),
                fmaxf(fmaxf(s[m][3][0], s[m][3][1]), fmaxf(s[m][3][2], s[m][3][3]))));
      mx = fmaxf(mx, __shfl_xor(mx, 16, 64));
      mx = fmaxf(mx, __shfl_xor(mx, 32, 64));
      if (!__all(mx - m_run[m] <= 10.0f)) {  // T13 defer-max: P bounded by 2^10
        float mn = fmaxf(m_run[m], mx);
        float corr = exp2f(m_run[m] - mn);
        m_run[m] = mn;
        l_run[m] *= corr;
        float cr[4];
#pragma unroll
        for (int r = 0; r < 4; ++r) cr[r] = __shfl(corr, 4 * lg + r, 64);
#pragma unroll
        for (int dt = 0; dt < 8; ++dt)
#pragma unroll
          for (int r = 0; r < 4; ++r) o[m][dt][r] *= cr[r];
      }
      float rsum = 0.f;
#pragma unroll
      for (int n = 0; n < 4; ++n) {
        float p0 = exp2f(s[m][n][0] - m_run[m]);
        float p1 = exp2f(s[m][n][1] - m_run[m]);
        float p2 = exp2f(s[m][n][2] - m_run[m]);
        float p3 = exp2f(s[m][n][3] - m_run[m]);
        rsum += (p0 + p1) + (p2 + p3);
        u32x2 pk;
        pk[0] = cvt_pk_bf16(p0, p1);
        pk[1] = cvt_pk_bf16(p2, p3);
        // contiguous kv run: P[q=m16+lr][kv=16n+4lg .. +3], one 8B write
        *(u32x2*)(pw + (m * 16 + lr) * 128 + ((32 * n + 8 * lg) ^ pkey[m])) = pk;
      }
      rsum += __shfl_xor(rsum, 16, 64);
      rsum += __shfl_xor(rsum, 32, 64);
      l_run[m] += rsum;
    }

    // ---- PV: O[32 q][128 d] += P[32][64] * V[64][128]; skip dead half ----
    const int nks = (t * 64 + 32 <= qmax) ? 2 : 1;
    __builtin_amdgcn_s_setprio(1);
    for (int ks = 0; ks < nks; ++ks) {
      bf16x8 pa[2];
#pragma unroll
      for (int m = 0; m < 2; ++m)
        pa[m] = *(const bf16x8*)(pw + (m * 16 + lr) * 128 +
                                 ((16 * lg + 64 * ks) ^ pkey[m]));
#pragma unroll
      for (int dt = 0; dt < 8; ++dt) {
        int d = dt * 16 + lr;
        bf16x8 vbf = *(const bf16x8*)(vb_ + d * 128 + ((16 * lg + 64 * ks) ^ swz16(d)));
#pragma unroll
        for (int m = 0; m < 2; ++m)
          o[m][dt] = __builtin_amdgcn_mfma_f32_16x16x32_bf16(pa[m], vbf, o[m][dt], 0, 0, 0);
      }
    }
    __builtin_amdgcn_s_setprio(0);

    if (t < tmax) STORE_V(nxt);
    __syncthreads();  // ONE barrier per tile
  }

  // ---- epilogue: O rows live at q = 4lg+r; stats at q = lr -> shfl transpose ----
#pragma unroll
  for (int m = 0; m < 2; ++m) {
    float linv[4];
#pragma unroll
    for (int r = 0; r < 4; ++r) linv[r] = 1.0f / __shfl(l_run[m], 4 * lg + r, 64);
#pragma unroll
    for (int r = 0; r < 4; ++r) {
      int qp_ = qb * QBLK + m * 16 + 4 * lg + r;
      if (qp_ < seq_len) {
        float* op = out + (size_t)(seq_start + qp_) * (H * DD) + h * DD + lr;
#pragma unroll
        for (int dt = 0; dt < 8; ++dt) op[dt * 16] = o[m][dt][r] * linv[r];
      }
    }
  }
#undef LOAD_T
#undef STORE_K
#undef STORE_V
}

extern "C" void kernel_launch(void* const* d_in, const int* in_sizes, int n_in,
                              void* d_out, int out_size, void* d_ws, size_t ws_size,
                              hipStream_t stream) {
  const float* q = (const float*)d_in[0];
  const float* k = (const float*)d_in[1];
  const float* v = (const float*)d_in[2];
  const int* cu = (const int*)d_in[3];
  float* out = (float*)d_out;
  const int B = in_sizes[3] - 1;  // 4
  const int inner_n = B * HKV;    // 32
  dim3 grid(NQB * inner_n);       // 1024 blocks, qb descending-major
  fa_kernel<<<grid, 256, 0, stream>>>(q, k, v, cu, out, inner_n);
}